// Round 8
// baseline (192.781 us; speedup 1.0000x reference)
//
#include <hip/hip_runtime.h>

// InfoCNECauchy: loss = mean_r log(sum_{j!=r} sim[r,j]) - mean_r log(sim[r, r^4096])
// sim = t^2/(d2+t^2), d2 = ||f_r||^2 + ||f_c||^2 - 2<f_r,f_c>, t=0.07
//
// R8: MX-fp8 GEMM. R5 structure (3 nodes, XCD banding, triangular tiles,
// fused Cauchy epilogue) with the K-loop moved to
// mfma_scale_f32_16x16x128_f8f6f4 (scales=1.0): 4 K-iters instead of 16,
// half the LDS/staging bytes, 2.25x MFMA rate per FLOP. R5's measured
// limiter was the LDS pipe (~75% busy) -- fp8 halves its traffic.
// Norms stay fp32 from original features; only the Gram matrix is fp8.

#define N2 8192
#define DIM 512
#define NT 64 /* 8192/128 tiles per dim */
#define NTILES (NT * (NT + 1) / 2)
#define T2 0.0049f

typedef float floatx4 __attribute__((ext_vector_type(4)));
typedef int intx4 __attribute__((ext_vector_type(4)));
typedef int intx8 __attribute__((ext_vector_type(8)));

__device__ __forceinline__ void load_to_lds16(const void* g, void* l) {
  auto gp = (const __attribute__((address_space(1))) void*)(reinterpret_cast<uintptr_t>(g));
  auto lp = (__attribute__((address_space(3))) void*)(reinterpret_cast<uintptr_t>(l));
  __builtin_amdgcn_global_load_lds(gp, lp, 16, 0, 0);
}

// ---- prep: fp32 -> fp8 e4m3 + row norms (fp32) + zero rowsum -------------
__global__ __launch_bounds__(256) void prep_kernel(const float* __restrict__ f,
                                                   unsigned int* __restrict__ fq,
                                                   float* __restrict__ sq,
                                                   float* __restrict__ rowsum) {
  const int t = threadIdx.x;
  if (t < 2) rowsum[blockIdx.x * 2 + t] = 0.f;
  const int row = blockIdx.x * 2 + (t >> 7);
  const int ci = (t & 127) * 4;
  const float4 v = *(const float4*)(f + (size_t)row * DIM + ci);
  // pack 4 floats -> 4 e4m3 bytes (OCP on gfx950)
  int w = __builtin_amdgcn_cvt_pk_fp8_f32(v.x, v.y, 0, false);
  w = __builtin_amdgcn_cvt_pk_fp8_f32(v.z, v.w, w, true);
  fq[((size_t)row * DIM + ci) >> 2] = (unsigned int)w;
  float s = v.x * v.x + v.y * v.y + v.z * v.z + v.w * v.w;
#pragma unroll
  for (int off = 1; off < 64; off <<= 1) s += __shfl_xor(s, off, 64);
  __shared__ float red[4];
  if ((t & 63) == 0) red[t >> 6] = s;
  __syncthreads();
  if ((t & 127) == 0) sq[row] = red[t >> 6] + red[(t >> 6) + 1];
}

// ---- fused MX-fp8 GEMM (upper triangle, XCD-banded) + Cauchy epilogue ----
__global__ __launch_bounds__(256) void gemm_kernel(const unsigned char* __restrict__ fq,
                                                   const float* __restrict__ sq,
                                                   float* __restrict__ rowsum,
                                                   float* __restrict__ spart) {
  // 128 rows x 128 B (one BK=128 slice), 16B chunks XOR-swizzled by row&7
  __shared__ unsigned char aT[128 * 128];  // 16 KB
  __shared__ unsigned char bT[128 * 128];  // 16 KB

  // XCD-banded tile decode (R5): x = blockIdx%8 (XCD), k = blockIdx/8.
  int by, bx;
  {
    const int x = blockIdx.x & 7;
    int kk = blockIdx.x >> 3;
    int band = x;
    const int n1 = 250 - 16 * x;
    if (kk >= n1) { kk -= n1; band = 15 - x; }
    const int by0 = band * 4;
    int bxx = by0;
    int cnt;
    while (kk >= (cnt = min(4, bxx - by0 + 1))) { kk -= cnt; ++bxx; }
    by = by0 + kk;
    bx = bxx;
  }
  const int brow = by * 128;
  const int bcol = bx * 128;
  const bool diag = (by == bx);

  const int t = threadIdx.x;
  const int lane = t & 63;
  const int w = t >> 6;
  const int wrow = (w >> 1) * 64;
  const int wcol = (w & 1) * 64;
  const int q4 = lane >> 4;  // 0..3 -> k-strip q4*32..+31
  const int lc = lane & 15;  // 0..15 -> row/col within 16-block

  floatx4 acc[4][4] = {};

  // staging: LDS slot q (16B units, q = it*256+t) holds (row = q>>3,
  // chunk c = (q&7) ^ (row&7)). Global row stride = DIM bytes (fp8).
  const unsigned char *gA[4], *gB[4];
#pragma unroll
  for (int it = 0; it < 4; ++it) {
    const int q = it * 256 + t;
    const int r = q >> 3;
    const int c = (q & 7) ^ (r & 7);
    gA[it] = fq + (size_t)(brow + r) * DIM + c * 16;
    gB[it] = fq + (size_t)(bcol + r) * DIM + c * 16;
  }

  // fragment reads: lane needs 32 B = k-chunks {q4*2, q4*2+1} of its row;
  // swizzled positions c0 = (q4*2)^(row&7), c1 = c0^1. row&7 == lc&7.
  const int c0 = (q4 * 2) ^ (lc & 7);

  for (int kt = 0; kt < DIM / 128; ++kt) {
#pragma unroll
    for (int it = 0; it < 4; ++it) {
      load_to_lds16(gA[it], &aT[t * 16 + it * 4096]);
      load_to_lds16(gB[it], &bT[t * 16 + it * 4096]);
    }
#pragma unroll
    for (int it = 0; it < 4; ++it) { gA[it] += 128; gB[it] += 128; }
    __syncthreads();

    intx8 bf[4];
#pragma unroll
    for (int mc = 0; mc < 4; ++mc) {
      const int row = wcol + mc * 16 + lc;
      const intx4 lo = *(const intx4*)&bT[row * 128 + c0 * 16];        // chunk q4*2
      const intx4 hi = *(const intx4*)&bT[row * 128 + (c0 ^ 1) * 16];  // chunk q4*2+1
      bf[mc] = __builtin_shufflevector(lo, hi, 0, 1, 2, 3, 4, 5, 6, 7);
    }
#pragma unroll
    for (int mr = 0; mr < 4; ++mr) {
      const int row = wrow + mr * 16 + lc;
      const intx4 lo = *(const intx4*)&aT[row * 128 + c0 * 16];
      const intx4 hi = *(const intx4*)&aT[row * 128 + (c0 ^ 1) * 16];
      const intx8 af = __builtin_shufflevector(lo, hi, 0, 1, 2, 3, 4, 5, 6, 7);
#pragma unroll
      for (int mc = 0; mc < 4; ++mc)
        acc[mr][mc] = __builtin_amdgcn_mfma_scale_f32_16x16x128_f8f6f4(
            af, bf[mc], acc[mr][mc], 0 /*fmtA=fp8*/, 0 /*fmtB=fp8*/,
            0, 127 /*scaleA=2^0*/, 0, 127 /*scaleB=2^0*/);
    }
    __syncthreads();
  }

  // Epilogue (R5 verbatim). C/D layout: col = lane&15, row = (lane>>4)*4+reg.
  float sqc[4];
#pragma unroll
  for (int mc = 0; mc < 4; ++mc) sqc[mc] = sq[bcol + wcol + mc * 16 + lc];

  float cs[4] = {0.f, 0.f, 0.f, 0.f};  // column partial sums (off-diag tiles)

#pragma unroll
  for (int mr = 0; mr < 4; ++mr) {
#pragma unroll
    for (int reg = 0; reg < 4; ++reg) {
      const int r = brow + wrow + mr * 16 + q4 * 4 + reg;
      const float sr = sq[r];
      const int pc = r ^ (N2 / 2);
      float rs = 0.f;
#pragma unroll
      for (int mc = 0; mc < 4; ++mc) {
        const int c = bcol + wcol + mc * 16 + lc;
        const float g = acc[mr][mc][reg];
        const float d2 = fmaxf(sr + sqc[mc] - 2.f * g, 0.f);
        const float s = T2 * __builtin_amdgcn_rcpf(d2 + T2);
        if (c != r) rs += s;  // diagonal excluded exactly (diag tiles only)
        cs[mc] += s;          // unused on diag tiles
        if (c == pc) { spart[r] = s; spart[pc] = s; }  // off-diag only, 1 lane
      }
#pragma unroll
      for (int off = 1; off < 16; off <<= 1) rs += __shfl_xor(rs, off, 64);
      if (lc == 0) atomicAdd(&rowsum[r], rs);
    }
  }

  if (!diag) {
#pragma unroll
    for (int mc = 0; mc < 4; ++mc) {
      float v = cs[mc];
      v += __shfl_xor(v, 16, 64);
      v += __shfl_xor(v, 32, 64);
      if (lane < 16) atomicAdd(&rowsum[bcol + wcol + mc * 16 + lane], v);
    }
  }
}

// ---- final scalar reduction ---------------------------------------------
__global__ __launch_bounds__(256) void final_kernel(const float* __restrict__ rowsum,
                                                    const float* __restrict__ spart,
                                                    float* __restrict__ out) {
  const int t = threadIdx.x;
  float a = 0.f;
  for (int r = t; r < N2; r += 256) a += logf(rowsum[r]) - logf(spart[r]);
#pragma unroll
  for (int off = 1; off < 64; off <<= 1) a += __shfl_xor(a, off, 64);
  __shared__ float red[4];
  if ((t & 63) == 0) red[t >> 6] = a;
  __syncthreads();
  if (t == 0) out[0] = (red[0] + red[1] + red[2] + red[3]) * (1.0f / (float)N2);
}

extern "C" void kernel_launch(void* const* d_in, const int* in_sizes, int n_in,
                              void* d_out, int out_size, void* d_ws, size_t ws_size,
                              hipStream_t stream) {
  const float* features = (const float*)d_in[0];
  float* out = (float*)d_out;

  char* ws = (char*)d_ws;
  unsigned int* fq = (unsigned int*)ws;                 // 4 MB (8192x512 fp8)
  float* sq = (float*)(ws + (size_t)N2 * DIM);          // 32 KB
  float* rowsum = sq + N2;                              // 32 KB
  float* spart = rowsum + N2;                           // 32 KB

  prep_kernel<<<N2 / 2, 256, 0, stream>>>(features, fq, sq, rowsum);
  gemm_kernel<<<NTILES, 256, 0, stream>>>((const unsigned char*)fq, sq, rowsum, spart);
  final_kernel<<<1, 256, 0, stream>>>(rowsum, spart, out);
}

// Round 9
// 156.354 us; speedup vs baseline: 1.2330x; 1.2330x over previous
//
#include <hip/hip_runtime.h>

// InfoCNECauchy: loss = mean_r log(sum_{j!=r} sim[r,j]) - mean_r log(sim[r, r^4096])
// sim = t^2/(d2+t^2), d2 = ||f_r||^2 + ||f_c||^2 - 2<f_r,f_c>, t=0.07
//
// R9: R5 body + true async prefetch: double-buffered LDS, ONE barrier per
// kt, prefetch of kt+1 issued AFTER the barrier that publishes kt. The
// end-of-body barrier's vmcnt(0) drain then waits on loads that had the
// whole compute phase to land (R5's limiter: exposed L2 latency at the
// staging barrier with only ~2 blocks/CU of overlap). Everything else
// (XOR swizzle 0-conflict, XCD banding, triangular tiles, epilogue,
// 3 nodes) is R5 verbatim. fp8 (R8) is dead: 212 total regs -> 1 block/CU.

#define N2 8192
#define DIM 512
#define NT 64 /* 8192/128 tiles per dim */
#define NTILES (NT * (NT + 1) / 2)
#define T2 0.0049f

typedef float floatx4 __attribute__((ext_vector_type(4)));
typedef __bf16 bf16x8 __attribute__((ext_vector_type(8)));
typedef __bf16 bf16x4 __attribute__((ext_vector_type(4)));

__device__ __forceinline__ void load_to_lds16(const void* g, void* l) {
  auto gp = (const __attribute__((address_space(1))) void*)(reinterpret_cast<uintptr_t>(g));
  auto lp = (__attribute__((address_space(3))) void*)(reinterpret_cast<uintptr_t>(l));
  __builtin_amdgcn_global_load_lds(gp, lp, 16, 0, 0);
}

// ---- prep: fp32 -> bf16 + row norms + zero rowsum ------------------------
__global__ __launch_bounds__(256) void prep_kernel(const float* __restrict__ f,
                                                   __bf16* __restrict__ fbf,
                                                   float* __restrict__ sq,
                                                   float* __restrict__ rowsum) {
  const int t = threadIdx.x;
  if (t < 2) rowsum[blockIdx.x * 2 + t] = 0.f;
  const int row = blockIdx.x * 2 + (t >> 7);
  const int ci = (t & 127) * 4;
  const float4 v = *(const float4*)(f + (size_t)row * DIM + ci);
  bf16x4 b;
  b[0] = (__bf16)v.x; b[1] = (__bf16)v.y; b[2] = (__bf16)v.z; b[3] = (__bf16)v.w;
  *(bf16x4*)(fbf + (size_t)row * DIM + ci) = b;
  float s = v.x * v.x + v.y * v.y + v.z * v.z + v.w * v.w;
#pragma unroll
  for (int off = 1; off < 64; off <<= 1) s += __shfl_xor(s, off, 64);
  __shared__ float red[4];
  if ((t & 63) == 0) red[t >> 6] = s;
  __syncthreads();
  if ((t & 127) == 0) sq[row] = red[t >> 6] + red[(t >> 6) + 1];
}

// ---- fused GEMM (upper triangle, XCD-banded, dbuf) + Cauchy epilogue -----
__global__ __launch_bounds__(256) void gemm_kernel(const __bf16* __restrict__ fbf,
                                                   const float* __restrict__ sq,
                                                   float* __restrict__ rowsum,
                                                   float* __restrict__ spart) {
  __shared__ __bf16 aT[2][128 * 32];  // double-buffered, XOR-swizzled
  __shared__ __bf16 bT[2][128 * 32];

  // XCD-banded tile decode: x = blockIdx%8 (XCD), k = blockIdx/8 (0..259).
  int by, bx;
  {
    const int x = blockIdx.x & 7;
    int kk = blockIdx.x >> 3;
    int band = x;
    const int n1 = 250 - 16 * x;
    if (kk >= n1) { kk -= n1; band = 15 - x; }
    const int by0 = band * 4;
    int bxx = by0;
    int cnt;
    while (kk >= (cnt = min(4, bxx - by0 + 1))) { kk -= cnt; ++bxx; }
    by = by0 + kk;
    bx = bxx;
  }
  const int brow = by * 128;
  const int bcol = bx * 128;
  const bool diag = (by == bx);

  const int t = threadIdx.x;
  const int lane = t & 63;
  const int w = t >> 6;
  const int wrow = (w >> 1) * 64;
  const int wcol = (w & 1) * 64;
  const int q4 = lane >> 4;  // 0..3
  const int lc = lane & 15;  // 0..15

  floatx4 acc[4][4] = {};

  // staging lane -> (global row, 16B chunk) under XOR swizzle:
  // LDS slot (rp, u') holds global (row = rp*2 + (u>>2), chunk = u&3), u = u'^(rp&7)
  const __bf16 *gA[2], *gB[2];
#pragma unroll
  for (int it = 0; it < 2; ++it) {
    const int slot = it * 256 + t;
    const int rp = slot >> 3;
    const int u = (slot & 7) ^ (rp & 7);
    const int gr = rp * 2 + (u >> 2);
    const int go = (u & 3) * 8;
    gA[it] = fbf + (size_t)(brow + gr) * DIM + go;
    gB[it] = fbf + (size_t)(bcol + gr) * DIM + go;
  }

  // fragment-read swizzle: u = (rr&1)*4+q4, u' = u ^ ((rr>>1)&7); rr = lc here.
  const int up = (((lc & 1) * 4) + q4) ^ (lc >> 1);
  const int rhalf = lc >> 1;

  // preload kt=0 into buffer 0
#pragma unroll
  for (int it = 0; it < 2; ++it) {
    load_to_lds16(gA[it], &aT[0][t * 8 + it * 2048]);
    load_to_lds16(gB[it], &bT[0][t * 8 + it * 2048]);
  }
  __syncthreads();  // buffer 0 ready

  for (int kt = 0; kt < DIM / 32; ++kt) {
    const int cur = kt & 1;
    // async prefetch of kt+1 into the other buffer (issued AFTER the
    // barrier; drained by the END-of-body barrier, hidden behind compute)
    if (kt + 1 < DIM / 32) {
      const int k0 = (kt + 1) * 32;
#pragma unroll
      for (int it = 0; it < 2; ++it) {
        load_to_lds16(gA[it] + k0, &aT[cur ^ 1][t * 8 + it * 2048]);
        load_to_lds16(gB[it] + k0, &bT[cur ^ 1][t * 8 + it * 2048]);
      }
    }
    bf16x8 af[4], bfr[4];
#pragma unroll
    for (int mr = 0; mr < 4; ++mr)
      af[mr] = *(const bf16x8*)&aT[cur][((wrow >> 1) + mr * 8 + rhalf) * 64 + up * 8];
#pragma unroll
    for (int mc = 0; mc < 4; ++mc)
      bfr[mc] = *(const bf16x8*)&bT[cur][((wcol >> 1) + mc * 8 + rhalf) * 64 + up * 8];
#pragma unroll
    for (int mr = 0; mr < 4; ++mr)
#pragma unroll
      for (int mc = 0; mc < 4; ++mc)
        acc[mr][mc] =
            __builtin_amdgcn_mfma_f32_16x16x32_bf16(af[mr], bfr[mc], acc[mr][mc], 0, 0, 0);
    // one barrier per kt: publishes buf cur^1 (prefetch) and retires buf cur
    __syncthreads();
  }

  // Epilogue. C/D layout: col = lane&15, row = (lane>>4)*4 + reg.
  float sqc[4];
#pragma unroll
  for (int mc = 0; mc < 4; ++mc) sqc[mc] = sq[bcol + wcol + mc * 16 + lc];

  float cs[4] = {0.f, 0.f, 0.f, 0.f};  // column partial sums (off-diag tiles)

#pragma unroll
  for (int mr = 0; mr < 4; ++mr) {
#pragma unroll
    for (int reg = 0; reg < 4; ++reg) {
      const int r = brow + wrow + mr * 16 + q4 * 4 + reg;
      const float sr = sq[r];
      const int pc = r ^ (N2 / 2);
      float rs = 0.f;
#pragma unroll
      for (int mc = 0; mc < 4; ++mc) {
        const int c = bcol + wcol + mc * 16 + lc;
        const float g = acc[mr][mc][reg];
        const float d2 = fmaxf(sr + sqc[mc] - 2.f * g, 0.f);
        const float s = T2 * __builtin_amdgcn_rcpf(d2 + T2);
        if (c != r) rs += s;  // diagonal excluded exactly (diag tiles only)
        cs[mc] += s;          // unused on diag tiles
        if (c == pc) { spart[r] = s; spart[pc] = s; }  // off-diag only, 1 lane
      }
#pragma unroll
      for (int off = 1; off < 16; off <<= 1) rs += __shfl_xor(rs, off, 64);
      if (lc == 0) atomicAdd(&rowsum[r], rs);
    }
  }

  if (!diag) {
#pragma unroll
    for (int mc = 0; mc < 4; ++mc) {
      float v = cs[mc];
      v += __shfl_xor(v, 16, 64);
      v += __shfl_xor(v, 32, 64);
      if (lane < 16) atomicAdd(&rowsum[bcol + wcol + mc * 16 + lane], v);
    }
  }
}

// ---- final scalar reduction ---------------------------------------------
__global__ __launch_bounds__(256) void final_kernel(const float* __restrict__ rowsum,
                                                    const float* __restrict__ spart,
                                                    float* __restrict__ out) {
  const int t = threadIdx.x;
  float a = 0.f;
  for (int r = t; r < N2; r += 256) a += logf(rowsum[r]) - logf(spart[r]);
#pragma unroll
  for (int off = 1; off < 64; off <<= 1) a += __shfl_xor(a, off, 64);
  __shared__ float red[4];
  if ((t & 63) == 0) red[t >> 6] = a;
  __syncthreads();
  if (t == 0) out[0] = (red[0] + red[1] + red[2] + red[3]) * (1.0f / (float)N2);
}

extern "C" void kernel_launch(void* const* d_in, const int* in_sizes, int n_in,
                              void* d_out, int out_size, void* d_ws, size_t ws_size,
                              hipStream_t stream) {
  const float* features = (const float*)d_in[0];
  float* out = (float*)d_out;

  char* ws = (char*)d_ws;
  __bf16* fbf = (__bf16*)ws;                                     // 8 MB
  float* sq = (float*)(ws + (size_t)N2 * DIM * sizeof(__bf16));  // 32 KB
  float* rowsum = sq + N2;                                       // 32 KB
  float* spart = rowsum + N2;                                    // 32 KB

  prep_kernel<<<N2 / 2, 256, 0, stream>>>(features, fbf, sq, rowsum);
  gemm_kernel<<<NTILES, 256, 0, stream>>>(fbf, sq, rowsum, spart);
  final_kernel<<<1, 256, 0, stream>>>(rowsum, spart, out);
}